// Round 2
// 3494.995 us; speedup vs baseline: 1.5881x; 1.5881x over previous
//
#include <hip/hip_runtime.h>
#include <math.h>

static const int PRED  = 100000;
static const int TOTAL = 120000;
static const int ITEM  = 100000;
static const int NUI   = PRED + ITEM;    // 200000
static const int NODES = TOTAL + ITEM;   // 220000
#define BN_EPS 1e-5f

__device__ inline float lrelu(float v, float s) { return v > 0.f ? v : s * v; }

// ---------------- batchnorm: coalesced grid-strided stats + per-block atomics ----------------
__global__ void k_bn_stats(const float* __restrict__ x, int n, float* __restrict__ sums) {
  __shared__ float ls[256], ls2[256];
  int t = threadIdx.x;
  int col = t & 63;
  float s = 0.f, s2 = 0.f;
  for (int r = blockIdx.x * 4 + (t >> 6); r < n; r += gridDim.x * 4) {
    float v = x[(size_t)r * 64 + col];
    s += v; s2 += v * v;
  }
  ls[t] = s; ls2[t] = s2;
  __syncthreads();
  if (t < 64) {
    atomicAdd(&sums[t],      ls[t] + ls[t + 64] + ls[t + 128] + ls[t + 192]);
    atomicAdd(&sums[64 + t], ls2[t] + ls2[t + 64] + ls2[t + 128] + ls2[t + 192]);
  }
}

__global__ void k_bn_apply(const float* __restrict__ x, float* __restrict__ y,
                           const float* __restrict__ sums,
                           const float* __restrict__ g, const float* __restrict__ b,
                           int n, int relu) {
  size_t tot = (size_t)n * 64;
  size_t i = (size_t)blockIdx.x * blockDim.x + threadIdx.x;
  size_t st = (size_t)gridDim.x * blockDim.x;
  float inv_n = 1.f / (float)n;
  for (; i < tot; i += st) {
    int c = (int)(i & 63);
    float mean = sums[c] * inv_n;
    float var = fmaxf(sums[64 + c] * inv_n - mean * mean, 0.f);
    float o = (x[i] - mean) * rsqrtf(var + BN_EPS) * g[c] + b[c];
    if (relu) o = lrelu(o, 0.01f);
    y[i] = o;
  }
}

// bn0: rows [0,TOTAL) -> e_tot; rows [TOTAL,NODES) -> uie[PRED..NUI); rows [0,PRED) also -> uie
__global__ void k_bn0_apply(const float* __restrict__ x, float* __restrict__ e_tot,
                            float* __restrict__ uie, const float* __restrict__ sums,
                            const float* __restrict__ g, const float* __restrict__ b) {
  size_t tot = (size_t)NODES * 64;
  size_t i = (size_t)blockIdx.x * blockDim.x + threadIdx.x;
  size_t st = (size_t)gridDim.x * blockDim.x;
  float inv_n = 1.f / (float)NODES;
  for (; i < tot; i += st) {
    int c = (int)(i & 63);
    size_t row = i >> 6;
    float mean = sums[c] * inv_n;
    float var = fmaxf(sums[64 + c] * inv_n - mean * mean, 0.f);
    float o = (x[i] - mean) * rsqrtf(var + BN_EPS) * g[c] + b[c];
    if (row < (size_t)TOTAL) e_tot[i] = o;
    else uie[((row - TOTAL) + PRED) * 64 + c] = o;
    if (row < (size_t)PRED) uie[i] = o;
  }
}

// ---------------- GEMM: C[n x 64] = A[n x 64] @ W[64 x 64] (+bias)(+=)(lrelu) ----------------
__global__ __launch_bounds__(256) void k_gemm64(const float* __restrict__ A,
                                                const float* __restrict__ Wm,
                                                const float* __restrict__ bias,
                                                float* __restrict__ C,
                                                int n, int accumulate, int relu) {
  __shared__ float AsT[64][68];
  __shared__ float Ws[64][68];
  int t = threadIdx.x;
  int row0 = blockIdx.x * 64;
  for (int i = t; i < 4096; i += 256) {
    int r = i >> 6, c = i & 63;
    Ws[r][c] = Wm[i];
    int gr = row0 + r;
    AsT[c][r] = (gr < n) ? A[(size_t)gr * 64 + c] : 0.f;
  }
  __syncthreads();
  int cg = (t & 15) * 4;
  int rg = (t >> 4) * 4;
  float acc[4][4];
  float b0 = 0.f, b1 = 0.f, b2v = 0.f, b3 = 0.f;
  if (bias) { b0 = bias[cg]; b1 = bias[cg + 1]; b2v = bias[cg + 2]; b3 = bias[cg + 3]; }
  for (int i = 0; i < 4; i++) { acc[i][0] = b0; acc[i][1] = b1; acc[i][2] = b2v; acc[i][3] = b3; }
  for (int k = 0; k < 64; ++k) {
    float4 w = *(const float4*)&Ws[k][cg];
    float4 a = *(const float4*)&AsT[k][rg];
    acc[0][0] += a.x * w.x; acc[0][1] += a.x * w.y; acc[0][2] += a.x * w.z; acc[0][3] += a.x * w.w;
    acc[1][0] += a.y * w.x; acc[1][1] += a.y * w.y; acc[1][2] += a.y * w.z; acc[1][3] += a.y * w.w;
    acc[2][0] += a.z * w.x; acc[2][1] += a.z * w.y; acc[2][2] += a.z * w.z; acc[2][3] += a.z * w.w;
    acc[3][0] += a.w * w.x; acc[3][1] += a.w * w.y; acc[3][2] += a.w * w.z; acc[3][3] += a.w * w.w;
  }
  for (int i = 0; i < 4; ++i) {
    int gr = row0 + rg + i;
    if (gr < n) {
      float4 o; o.x = acc[i][0]; o.y = acc[i][1]; o.z = acc[i][2]; o.w = acc[i][3];
      if (accumulate) {
        float4 p = *(const float4*)&C[(size_t)gr * 64 + cg];
        o.x += p.x; o.y += p.y; o.z += p.z; o.w += p.w;
      }
      if (relu) { o.x = lrelu(o.x, 0.01f); o.y = lrelu(o.y, 0.01f); o.z = lrelu(o.z, 0.01f); o.w = lrelu(o.w, 0.01f); }
      *(float4*)&C[(size_t)gr * 64 + cg] = o;
    }
  }
}

// ---------------- CSR build: histogram + scan + permute ----------------
__global__ void k_hist(const int* __restrict__ dst, int* __restrict__ counts, int E) {
  int i = blockIdx.x * blockDim.x + threadIdx.x;
  int st = gridDim.x * blockDim.x;
  for (; i < E; i += st) atomicAdd(&counts[dst[i]], 1);
}

__global__ void k_scan_part(const int* __restrict__ counts, int* __restrict__ bsums, int n) {
  __shared__ int sh[256];
  int t = threadIdx.x;
  int i = blockIdx.x * 256 + t;
  sh[t] = (i < n) ? counts[i] : 0;
  __syncthreads();
  for (int o = 128; o; o >>= 1) {
    if (t < o) sh[t] += sh[t + o];
    __syncthreads();
  }
  if (t == 0) bsums[blockIdx.x] = sh[0];
}

__global__ void k_scan_tops(int* __restrict__ bsums, int nb) {
  __shared__ int sh[256];
  int t = threadIdx.x;
  int carry = 0;
  for (int base = 0; base < nb; base += 256) {
    int i = base + t;
    int v = (i < nb) ? bsums[i] : 0;
    __syncthreads();
    sh[t] = v;
    __syncthreads();
    for (int o = 1; o < 256; o <<= 1) {
      int tv = (t >= o) ? sh[t - o] : 0;
      __syncthreads();
      sh[t] += tv;
      __syncthreads();
    }
    int incl = sh[t];
    int total = sh[255];
    if (i < nb) bsums[i] = incl - v + carry;
    carry += total;
  }
}

// cnts[i] also becomes cursor[i] (= exclusive prefix) in place; offs gets n+1 entries
__global__ void k_scan_apply(int* __restrict__ cnts, const int* __restrict__ bsums,
                             int* __restrict__ offs, int n) {
  __shared__ int sh[256];
  int t = threadIdx.x;
  int i = blockIdx.x * 256 + t;
  int v = (i < n) ? cnts[i] : 0;
  sh[t] = v;
  __syncthreads();
  for (int o = 1; o < 256; o <<= 1) {
    int tv = (t >= o) ? sh[t - o] : 0;
    __syncthreads();
    sh[t] += tv;
    __syncthreads();
  }
  int excl = sh[t] - v + bsums[blockIdx.x];
  if (i <= n) offs[i] = excl;
  if (i < n) cnts[i] = excl;
}

__global__ void k_permute(const int* __restrict__ src, const int* __restrict__ dst,
                          int* __restrict__ cursor, int* __restrict__ csr, int E) {
  int i = blockIdx.x * blockDim.x + threadIdx.x;
  int st = gridDim.x * blockDim.x;
  for (; i < E; i += st) {
    int pos = atomicAdd(&cursor[dst[i]], 1);
    csr[pos] = src[i];
  }
}

__global__ void k_dinv(const int* __restrict__ offs, float* __restrict__ dinv, int n) {
  int i = blockIdx.x * blockDim.x + threadIdx.x;
  int st = gridDim.x * blockDim.x;
  for (; i < n; i += st) dinv[i] = rsqrtf(fmaxf((float)(offs[i + 1] - offs[i]), 1.f));
}

// ---------------- fused GAT: one wave per dst row, online softmax, no atomics ----------------
__global__ __launch_bounds__(256) void k_gat_fused(const float* __restrict__ fs,
                                                   const float* __restrict__ fd,
                                                   const float* __restrict__ attn,
                                                   const int* __restrict__ offs,
                                                   const int* __restrict__ csr_src,
                                                   float* __restrict__ out, int n) {
  int lane = threadIdx.x & 63;
  int wid = (blockIdx.x * blockDim.x + threadIdx.x) >> 6;
  int nw = (gridDim.x * blockDim.x) >> 6;
  float ak = attn[lane];
  for (int r = wid; r < n; r += nw) {
    int beg = offs[r], end = offs[r + 1];
    float fdv = fd[(size_t)r * 64 + lane];
    float m = -INFINITY, den = 0.f, acc = 0.f;
    int s = (beg < end) ? csr_src[beg] : 0;
    for (int e = beg; e < end; ++e) {
      int snext = (e + 1 < end) ? csr_src[e + 1] : 0;
      float fsv = fs[(size_t)s * 64 + lane];
      float w = lrelu(fsv + fdv, 0.2f) * ak;
      for (int o = 32; o; o >>= 1) w += __shfl_xor(w, o);
      float nm = fmaxf(m, w);
      float sc = __expf(m - nm);   // m=-inf on first iter -> sc=0
      float p = __expf(w - nm);
      den = den * sc + p;
      acc = acc * sc + p * fsv;
      m = nm;
      s = snext;
    }
    out[(size_t)r * 64 + lane] = (end > beg) ? lrelu(acc / den, 0.01f) : 0.f;
  }
}

// ---------------- fused Cheb: gather-accumulate + recurrence, no atomics ----------------
// mode 1: out = c*(v_r - acc) - v_r                (v == T0)
// mode 2: out = 2*(c*(v_r - acc) - v_r) - t0_r     (v == T1)
__global__ __launch_bounds__(256) void k_cheb_fused(const float* __restrict__ v,
                                                    const float* __restrict__ t0,
                                                    const float* __restrict__ dinv,
                                                    const int* __restrict__ offs,
                                                    const int* __restrict__ csr_src,
                                                    float* __restrict__ out,
                                                    const float* __restrict__ lamf,
                                                    int n, int mode) {
  int lane = threadIdx.x & 63;
  int wid = (blockIdx.x * blockDim.x + threadIdx.x) >> 6;
  int nw = (gridDim.x * blockDim.x) >> 6;
  float c = 2.f / lamf[0];
  for (int r = wid; r < n; r += nw) {
    int beg = offs[r], end = offs[r + 1];
    float dr = dinv[r];
    float acc = 0.f;
    int s = (beg < end) ? csr_src[beg] : 0;
    for (int e = beg; e < end; ++e) {
      int snext = (e + 1 < end) ? csr_src[e + 1] : 0;
      float ns = dinv[s] * dr;
      acc += ns * v[(size_t)s * 64 + lane];
      s = snext;
    }
    float vr = v[(size_t)r * 64 + lane];
    float o = c * (vr - acc) - vr;
    if (mode == 2) o = 2.f * o - t0[(size_t)r * 64 + lane];
    out[(size_t)r * 64 + lane] = o;
  }
}

// ---------------- misc fused (wave per row) ----------------
__global__ void k_mask_select(const float* __restrict__ i2u, const float* __restrict__ pred,
                              float* __restrict__ out, int n) {
  int lane = threadIdx.x & 63;
  int wid = (blockIdx.x * blockDim.x + threadIdx.x) >> 6;
  int nw = (gridDim.x * blockDim.x) >> 6;
  for (int r = wid; r < n; r += nw) {
    float v = i2u[(size_t)r * 64 + lane];
    float s = v;
    for (int o = 32; o; o >>= 1) s += __shfl_xor(s, o);
    out[(size_t)r * 64 + lane] = (s != 0.f) ? v : pred[(size_t)r * 64 + lane];
  }
}

// out = a * b * softmax_row(a)
__global__ void k_softmax_mul(const float* __restrict__ a, const float* __restrict__ b,
                              float* __restrict__ out, int n) {
  int lane = threadIdx.x & 63;
  int wid = (blockIdx.x * blockDim.x + threadIdx.x) >> 6;
  int nw = (gridDim.x * blockDim.x) >> 6;
  for (int r = wid; r < n; r += nw) {
    size_t idx = (size_t)r * 64 + lane;
    float av = a[idx];
    float mx = av;
    for (int o = 32; o; o >>= 1) mx = fmaxf(mx, __shfl_xor(mx, o));
    float e = expf(av - mx);
    float s = e;
    for (int o = 32; o; o >>= 1) s += __shfl_xor(s, o);
    out[idx] = av * b[idx] * (e / s);
  }
}

// ---------------- host ----------------
extern "C" void kernel_launch(void* const* d_in, const int* in_sizes, int n_in,
                              void* d_out, int out_size, void* d_ws, size_t ws_size,
                              hipStream_t stream) {
  const float* emb      = (const float*)d_in[0];
  const float* bn0_g    = (const float*)d_in[1];
  const float* bn0_b    = (const float*)d_in[2];
  const float* gat_Wl   = (const float*)d_in[3];
  const float* gat_bl   = (const float*)d_in[4];
  const float* gat_Wr   = (const float*)d_in[5];
  const float* gat_br   = (const float*)d_in[6];
  const float* gat_attn = (const float*)d_in[7];
  const float* cheb_W   = (const float*)d_in[8];
  const float* cheb_b   = (const float*)d_in[9];
  const float* mlp_W    = (const float*)d_in[10];
  const float* mlp_b    = (const float*)d_in[11];
  const float* mlp_g    = (const float*)d_in[12];
  const float* mlp_beta = (const float*)d_in[13];
  const float* lam      = (const float*)d_in[14];
  const int* u2i_src = (const int*)d_in[15];
  const int* u2i_dst = (const int*)d_in[16];
  const int* rc_src  = (const int*)d_in[17];
  const int* rc_dst  = (const int*)d_in[18];
  const int* i2u_src = (const int*)d_in[19];
  const int* i2u_dst = (const int*)d_in[20];
  const int* sn_src  = (const int*)d_in[22];
  const int* sn_dst  = (const int*)d_in[23];
  const int* snn_src = (const int*)d_in[24];
  const int* snn_dst = (const int*)d_in[25];
  int E_u2i = in_sizes[15], E_rc = in_sizes[17], E_i2u = in_sizes[19];
  int E_sn = in_sizes[22], E_snn = in_sizes[24];

  float* Wp = (float*)d_ws;
  size_t off = 0;
  auto alloc = [&](size_t nf) { float* p = Wp + off; off += nf; return p; };
  float* e_tot = alloc((size_t)TOTAL * 64);     // 30.7 MB
  float* POOL  = alloc((size_t)600000 * 64);    // 153.6 MB
  int*   csr_src = (int*)alloc(1500000);        // 6 MB
  int*   offs    = (int*)alloc(200064);
  int*   cnt_cur = (int*)alloc(200064);
  int*   bsums   = (int*)alloc(1024);
  float* dinv  = alloc(TOTAL);
  float* sums  = alloc(128);
  // total ~192.4 MB, same footprint as the previously passing version

  auto R = [&](size_t row) { return POOL + row * 64; };
  float* outP = (float*)d_out;                  // f32 output
  float* outS = outP + (size_t)PRED * 64;

  auto gemm = [&](const float* A, const float* Wm, const float* bias, float* C, int n, int acc, int relu) {
    k_gemm64<<<(n + 63) / 64, 256, 0, stream>>>(A, Wm, bias, C, n, acc, relu);
  };
  auto stats = [&](const float* x, int n) {
    hipMemsetAsync(sums, 0, 128 * 4, stream);
    k_bn_stats<<<512, 256, 0, stream>>>(x, n, sums);
  };
  auto build_csr = [&](const int* src, const int* dst, int E, int n) {
    int NB = (n + 256) / 256;   // covers n+1 elements
    hipMemsetAsync(cnt_cur, 0, (size_t)n * 4, stream);
    k_hist<<<2048, 256, 0, stream>>>(dst, cnt_cur, E);
    k_scan_part<<<NB, 256, 0, stream>>>(cnt_cur, bsums, n);
    k_scan_tops<<<1, 256, 0, stream>>>(bsums, NB);
    k_scan_apply<<<NB, 256, 0, stream>>>(cnt_cur, bsums, offs, n);
    k_permute<<<2048, 256, 0, stream>>>(src, dst, cnt_cur, csr_src, E);
  };
  auto gat = [&](int i, const float* fs, const float* fd, int n, float* out) {
    k_gat_fused<<<(n + 3) / 4, 256, 0, stream>>>(fs, fd, gat_attn + i * 64, offs, csr_src, out, n);
  };

  // ---- bn0 ----
  stats(emb, NODES);
  k_bn0_apply<<<2048, 256, 0, stream>>>(emb, e_tot, R(0), sums, bn0_g, bn0_b);

  // ---- gat0: u2i_emb -> R(0) (in-place over uie) ----
  build_csr(u2i_src, u2i_dst, E_u2i, NUI);
  gemm(R(0), gat_Wl + 0 * 4096, gat_bl + 0, R(200000), NUI, 0, 0);
  gemm(R(0), gat_Wr + 0 * 4096, gat_br + 0, R(400000), NUI, 0, 0);
  gat(0, R(200000), R(400000), NUI, R(0));

  // ---- gat1: iie -> R(0)[:PRED] ----
  build_csr(rc_src, rc_dst, E_rc, NUI);
  gemm(R(0), gat_Wl + 1 * 4096, gat_bl + 64, R(200000), NUI, 0, 0);
  gemm(R(0), gat_Wr + 1 * 4096, gat_br + 64, R(400000), NUI, 0, 0);
  gat(1, R(200000), R(400000), NUI, R(0));

  // ---- gat2: i2u_emb -> R(300000) ----
  build_csr(i2u_src, i2u_dst, E_i2u, PRED);
  gemm(e_tot, gat_Wl + 2 * 4096, gat_bl + 128, R(200000), PRED, 0, 0);
  gemm(e_tot, gat_Wr + 2 * 4096, gat_br + 128, R(400000), PRED, 0, 0);
  gat(2, R(200000), R(400000), PRED, R(300000));

  // ---- soc -> R(400000) ----
  k_mask_select<<<2048, 256, 0, stream>>>(R(300000), e_tot, R(400000), PRED);

  // ---- gat3: sie -> R(300000) ----
  build_csr(sn_src, sn_dst, E_sn, PRED);
  gemm(R(400000), gat_Wl + 3 * 4096, gat_bl + 192, R(200000), PRED, 0, 0);
  gemm(R(400000), gat_Wr + 3 * 4096, gat_br + 192, R(500000), PRED, 0, 0);
  gat(3, R(200000), R(500000), PRED, R(300000));

  // ---- mlp0: user_item -> R(0)[:PRED] (via scratch R(100000)) ----
  gemm(R(0), mlp_W + 0 * 8192, mlp_b + 0, R(100000), PRED, 0, 0);
  gemm(R(300000), mlp_W + 0 * 8192 + 4096, nullptr, R(100000), PRED, 1, 0);
  stats(R(100000), PRED);
  k_bn_apply<<<2048, 256, 0, stream>>>(R(100000), R(0), sums, mlp_g + 0, mlp_beta + 0, PRED, 1);

  // ---- snn CSR (used by cheb x4 and gat4) ----
  build_csr(snn_src, snn_dst, E_snn, TOTAL);
  k_dinv<<<256, 256, 0, stream>>>(offs, dinv, TOTAL);

  auto cheb = [&](const float* T0, float* T1, float* T2, float* outC) {
    k_cheb_fused<<<(TOTAL + 3) / 4, 256, 0, stream>>>(T0, T0, dinv, offs, csr_src, T1, lam, TOTAL, 1);
    k_cheb_fused<<<(TOTAL + 3) / 4, 256, 0, stream>>>(T1, T0, dinv, offs, csr_src, T2, lam, TOTAL, 2);
    gemm(T0, cheb_W + 0,    cheb_b, outC, TOTAL, 0, 0);
    gemm(T1, cheb_W + 4096, nullptr, outC, TOTAL, 1, 0);
    gemm(T2, cheb_W + 8192, nullptr, outC, TOTAL, 1, 1);
  };
  cheb(e_tot, R(100000), R(220000), R(340000));       // h1 -> R(340000)
  cheb(R(340000), R(100000), R(220000), R(460000));   // h2 -> R(460000)

  // ---- gat4: user_social -> R(460000) ----
  gemm(R(460000), gat_Wl + 4 * 4096, gat_bl + 256, R(100000), TOTAL, 0, 0);
  gemm(R(460000), gat_Wr + 4 * 4096, gat_br + 256, R(220000), TOTAL, 0, 0);
  gat(4, R(100000), R(220000), TOTAL, R(460000));

  // ---- mlp1: h_uP -> R(100000) ----
  gemm(R(0), mlp_W + 1 * 8192, mlp_b + 64, R(100000), PRED, 0, 0);
  gemm(e_tot, mlp_W + 1 * 8192 + 4096, nullptr, R(100000), PRED, 1, 0);
  stats(R(100000), PRED);
  k_bn_apply<<<2048, 256, 0, stream>>>(R(100000), R(100000), sums, mlp_g + 64, mlp_beta + 64, PRED, 1);

  // ---- mlp2: h_uS -> R(200000) ----
  gemm(R(460000), mlp_W + 2 * 8192, mlp_b + 128, R(200000), PRED, 0, 0);
  gemm(e_tot, mlp_W + 2 * 8192 + 4096, nullptr, R(200000), PRED, 1, 0);
  stats(R(200000), PRED);
  k_bn_apply<<<2048, 256, 0, stream>>>(R(200000), R(200000), sums, mlp_g + 128, mlp_beta + 128, PRED, 1);

  // ---- final P ----
  k_softmax_mul<<<2048, 256, 0, stream>>>(R(100000), R(200000), R(300000), PRED);
  gemm(R(300000), mlp_W + 3 * 8192, mlp_b + 192, R(400000), PRED, 0, 0);
  gemm(R(100000), mlp_W + 3 * 8192 + 4096, nullptr, R(400000), PRED, 1, 0);
  stats(R(400000), PRED);
  k_bn_apply<<<2048, 256, 0, stream>>>(R(400000), outP, sums, mlp_g + 192, mlp_beta + 192, PRED, 1);

  // ---- final S ----
  k_softmax_mul<<<2048, 256, 0, stream>>>(R(200000), R(100000), R(300000), PRED);
  gemm(R(300000), mlp_W + 4 * 8192, mlp_b + 256, R(400000), PRED, 0, 0);
  gemm(R(200000), mlp_W + 4 * 8192 + 4096, nullptr, R(400000), PRED, 1, 0);
  stats(R(400000), PRED);
  k_bn_apply<<<2048, 256, 0, stream>>>(R(400000), outS, sums, mlp_g + 256, mlp_beta + 256, PRED, 1);
}

// Round 3
// 2833.406 us; speedup vs baseline: 1.9590x; 1.2335x over previous
//
#include <hip/hip_runtime.h>
#include <math.h>

static const int PRED  = 100000;
static const int TOTAL = 120000;
static const int ITEM  = 100000;
static const int NUI   = PRED + ITEM;    // 200000
static const int NODES = TOTAL + ITEM;   // 220000
#define BN_EPS 1e-5f
#define MNEG -1e30f
#define WNEG -2e30f

__device__ inline float lrelu(float v, float s) { return v > 0.f ? v : s * v; }

// ---------------- batchnorm: coalesced grid-strided stats + per-block atomics ----------------
__global__ void k_bn_stats(const float* __restrict__ x, int n, float* __restrict__ sums) {
  __shared__ float ls[256], ls2[256];
  int t = threadIdx.x;
  int col = t & 63;
  float s = 0.f, s2 = 0.f;
  for (int r = blockIdx.x * 4 + (t >> 6); r < n; r += gridDim.x * 4) {
    float v = x[(size_t)r * 64 + col];
    s += v; s2 += v * v;
  }
  ls[t] = s; ls2[t] = s2;
  __syncthreads();
  if (t < 64) {
    atomicAdd(&sums[t],      ls[t] + ls[t + 64] + ls[t + 128] + ls[t + 192]);
    atomicAdd(&sums[64 + t], ls2[t] + ls2[t + 64] + ls2[t + 128] + ls2[t + 192]);
  }
}

__global__ void k_bn_apply(const float* __restrict__ x, float* __restrict__ y,
                           const float* __restrict__ sums,
                           const float* __restrict__ g, const float* __restrict__ b,
                           int n, int relu) {
  size_t tot = (size_t)n * 64;
  size_t i = (size_t)blockIdx.x * blockDim.x + threadIdx.x;
  size_t st = (size_t)gridDim.x * blockDim.x;
  float inv_n = 1.f / (float)n;
  for (; i < tot; i += st) {
    int c = (int)(i & 63);
    float mean = sums[c] * inv_n;
    float var = fmaxf(sums[64 + c] * inv_n - mean * mean, 0.f);
    float o = (x[i] - mean) * rsqrtf(var + BN_EPS) * g[c] + b[c];
    if (relu) o = lrelu(o, 0.01f);
    y[i] = o;
  }
}

// bn0: rows [0,TOTAL) -> e_tot; rows [TOTAL,NODES) -> uie[PRED..NUI); rows [0,PRED) also -> uie
__global__ void k_bn0_apply(const float* __restrict__ x, float* __restrict__ e_tot,
                            float* __restrict__ uie, const float* __restrict__ sums,
                            const float* __restrict__ g, const float* __restrict__ b) {
  size_t tot = (size_t)NODES * 64;
  size_t i = (size_t)blockIdx.x * blockDim.x + threadIdx.x;
  size_t st = (size_t)gridDim.x * blockDim.x;
  float inv_n = 1.f / (float)NODES;
  for (; i < tot; i += st) {
    int c = (int)(i & 63);
    size_t row = i >> 6;
    float mean = sums[c] * inv_n;
    float var = fmaxf(sums[64 + c] * inv_n - mean * mean, 0.f);
    float o = (x[i] - mean) * rsqrtf(var + BN_EPS) * g[c] + b[c];
    if (row < (size_t)TOTAL) e_tot[i] = o;
    else uie[((row - TOTAL) + PRED) * 64 + c] = o;
    if (row < (size_t)PRED) uie[i] = o;
  }
}

// ---------------- GEMM: C[n x 64] = A[n x 64] @ W[64 x 64] (+bias)(+=)(lrelu) ----------------
// 128 rows/block, 128 threads, 8x8 per thread (VALU-bound, not LDS-bound)
__global__ __launch_bounds__(128) void k_gemm64(const float* __restrict__ A,
                                                const float* __restrict__ Wm,
                                                const float* __restrict__ bias,
                                                float* __restrict__ C,
                                                int n, int accumulate, int relu) {
  __shared__ float As[128][65];   // row-major; pad 65 spreads row-groups over banks
  __shared__ float Ws[64][68];
  int t = threadIdx.x;            // 0..127
  int row0 = blockIdx.x * 128;
  for (int i = t; i < 4096; i += 128) {
    Ws[i >> 6][i & 63] = Wm[i];
  }
  for (int i = t; i < 2048; i += 128) {
    int r = i >> 4;
    int c = (i & 15) * 4;
    int gr = row0 + r;
    float4 a;
    if (gr < n) a = *(const float4*)&A[(size_t)gr * 64 + c];
    else { a.x = a.y = a.z = a.w = 0.f; }
    As[r][c] = a.x; As[r][c + 1] = a.y; As[r][c + 2] = a.z; As[r][c + 3] = a.w;
  }
  __syncthreads();
  int cg = (t & 7) * 8;
  int rg = (t >> 3) * 8;
  float bb[8];
  if (bias) {
    *(float4*)&bb[0] = *(const float4*)&bias[cg];
    *(float4*)&bb[4] = *(const float4*)&bias[cg + 4];
  } else {
    for (int j = 0; j < 8; ++j) bb[j] = 0.f;
  }
  float acc[8][8];
  #pragma unroll
  for (int i = 0; i < 8; ++i)
    #pragma unroll
    for (int j = 0; j < 8; ++j) acc[i][j] = bb[j];
  for (int k = 0; k < 64; ++k) {
    float w[8], a[8];
    *(float4*)&w[0] = *(const float4*)&Ws[k][cg];
    *(float4*)&w[4] = *(const float4*)&Ws[k][cg + 4];
    #pragma unroll
    for (int i = 0; i < 8; ++i) a[i] = As[rg + i][k];
    #pragma unroll
    for (int i = 0; i < 8; ++i)
      #pragma unroll
      for (int j = 0; j < 8; ++j)
        acc[i][j] += a[i] * w[j];
  }
  #pragma unroll
  for (int i = 0; i < 8; ++i) {
    int gr = row0 + rg + i;
    if (gr < n) {
      float4 o0, o1;
      o0.x = acc[i][0]; o0.y = acc[i][1]; o0.z = acc[i][2]; o0.w = acc[i][3];
      o1.x = acc[i][4]; o1.y = acc[i][5]; o1.z = acc[i][6]; o1.w = acc[i][7];
      if (accumulate) {
        float4 p0 = *(const float4*)&C[(size_t)gr * 64 + cg];
        float4 p1 = *(const float4*)&C[(size_t)gr * 64 + cg + 4];
        o0.x += p0.x; o0.y += p0.y; o0.z += p0.z; o0.w += p0.w;
        o1.x += p1.x; o1.y += p1.y; o1.z += p1.z; o1.w += p1.w;
      }
      if (relu) {
        o0.x = lrelu(o0.x, 0.01f); o0.y = lrelu(o0.y, 0.01f); o0.z = lrelu(o0.z, 0.01f); o0.w = lrelu(o0.w, 0.01f);
        o1.x = lrelu(o1.x, 0.01f); o1.y = lrelu(o1.y, 0.01f); o1.z = lrelu(o1.z, 0.01f); o1.w = lrelu(o1.w, 0.01f);
      }
      *(float4*)&C[(size_t)gr * 64 + cg] = o0;
      *(float4*)&C[(size_t)gr * 64 + cg + 4] = o1;
    }
  }
}

// ---------------- CSR build: histogram + scan + permute ----------------
__global__ void k_hist(const int* __restrict__ dst, int* __restrict__ counts, int E) {
  int i = blockIdx.x * blockDim.x + threadIdx.x;
  int st = gridDim.x * blockDim.x;
  for (; i < E; i += st) atomicAdd(&counts[dst[i]], 1);
}

__global__ void k_scan_part(const int* __restrict__ counts, int* __restrict__ bsums, int n) {
  __shared__ int sh[256];
  int t = threadIdx.x;
  int i = blockIdx.x * 256 + t;
  sh[t] = (i < n) ? counts[i] : 0;
  __syncthreads();
  for (int o = 128; o; o >>= 1) {
    if (t < o) sh[t] += sh[t + o];
    __syncthreads();
  }
  if (t == 0) bsums[blockIdx.x] = sh[0];
}

__global__ void k_scan_tops(int* __restrict__ bsums, int nb) {
  __shared__ int sh[256];
  int t = threadIdx.x;
  int carry = 0;
  for (int base = 0; base < nb; base += 256) {
    int i = base + t;
    int v = (i < nb) ? bsums[i] : 0;
    __syncthreads();
    sh[t] = v;
    __syncthreads();
    for (int o = 1; o < 256; o <<= 1) {
      int tv = (t >= o) ? sh[t - o] : 0;
      __syncthreads();
      sh[t] += tv;
      __syncthreads();
    }
    int incl = sh[t];
    int total = sh[255];
    if (i < nb) bsums[i] = incl - v + carry;
    carry += total;
  }
}

// cnts[i] also becomes cursor[i] (= exclusive prefix) in place; offs gets n+1 entries
__global__ void k_scan_apply(int* __restrict__ cnts, const int* __restrict__ bsums,
                             int* __restrict__ offs, int n) {
  __shared__ int sh[256];
  int t = threadIdx.x;
  int i = blockIdx.x * 256 + t;
  int v = (i < n) ? cnts[i] : 0;
  sh[t] = v;
  __syncthreads();
  for (int o = 1; o < 256; o <<= 1) {
    int tv = (t >= o) ? sh[t - o] : 0;
    __syncthreads();
    sh[t] += tv;
    __syncthreads();
  }
  int excl = sh[t] - v + bsums[blockIdx.x];
  if (i <= n) offs[i] = excl;
  if (i < n) cnts[i] = excl;
}

__global__ void k_permute(const int* __restrict__ src, const int* __restrict__ dst,
                          int* __restrict__ cursor, int* __restrict__ csr, int E) {
  int i = blockIdx.x * blockDim.x + threadIdx.x;
  int st = gridDim.x * blockDim.x;
  for (; i < E; i += st) {
    int pos = atomicAdd(&cursor[dst[i]], 1);
    csr[pos] = src[i];
  }
}

__global__ void k_dinv(const int* __restrict__ offs, float* __restrict__ dinv, int n) {
  int i = blockIdx.x * blockDim.x + threadIdx.x;
  int st = gridDim.x * blockDim.x;
  for (; i < n; i += st) dinv[i] = rsqrtf(fmaxf((float)(offs[i + 1] - offs[i]), 1.f));
}

// ---------------- fused GAT v2: 4 edges/wave, 16 lanes/edge, float4/lane ----------------
__global__ __launch_bounds__(256) void k_gat_fused(const float* __restrict__ fs,
                                                   const float* __restrict__ fd,
                                                   const float* __restrict__ attn,
                                                   const int* __restrict__ offs,
                                                   const int* __restrict__ csr_src,
                                                   float* __restrict__ out, int n) {
  int lane = threadIdx.x & 63;
  int g  = lane >> 4;          // edge group 0..3
  int li = lane & 15;          // channel quad 0..15
  int c4 = li * 4;
  int wid = (blockIdx.x * blockDim.x + threadIdx.x) >> 6;
  int nw = (gridDim.x * blockDim.x) >> 6;
  float4 ak = *(const float4*)&attn[c4];
  for (int r = wid; r < n; r += nw) {
    int beg = offs[r], end = offs[r + 1];
    float4 fdv = *(const float4*)&fd[(size_t)r * 64 + c4];
    float m = MNEG, den = 0.f;
    float4 acc; acc.x = acc.y = acc.z = acc.w = 0.f;
    for (int e4 = beg; e4 < end; e4 += 4) {
      int myE = e4 + g;
      bool act = myE < end;
      int s = act ? csr_src[myE] : 0;
      float4 fsv = *(const float4*)&fs[(size_t)s * 64 + c4];
      float w = ak.x * lrelu(fsv.x + fdv.x, 0.2f)
              + ak.y * lrelu(fsv.y + fdv.y, 0.2f)
              + ak.z * lrelu(fsv.z + fdv.z, 0.2f)
              + ak.w * lrelu(fsv.w + fdv.w, 0.2f);
      w += __shfl_xor(w, 1);
      w += __shfl_xor(w, 2);
      w += __shfl_xor(w, 4);
      w += __shfl_xor(w, 8);
      if (!act) w = WNEG;
      float nm = fmaxf(m, w);
      float sc = __expf(m - nm);   // finite sentinels: never inf-inf
      float p  = __expf(w - nm);
      den = den * sc + p;
      acc.x = acc.x * sc + p * fsv.x;
      acc.y = acc.y * sc + p * fsv.y;
      acc.z = acc.z * sc + p * fsv.z;
      acc.w = acc.w * sc + p * fsv.w;
      m = nm;
    }
    // merge the 4 groups (xor 16, then xor 32)
    #pragma unroll
    for (int o = 16; o < 64; o <<= 1) {
      float mo   = __shfl_xor(m, o);
      float deno = __shfl_xor(den, o);
      float ax = __shfl_xor(acc.x, o);
      float ay = __shfl_xor(acc.y, o);
      float az = __shfl_xor(acc.z, o);
      float aw = __shfl_xor(acc.w, o);
      float nm = fmaxf(m, mo);
      float sc = __expf(m - nm);
      float so = __expf(mo - nm);
      den = den * sc + deno * so;
      acc.x = acc.x * sc + ax * so;
      acc.y = acc.y * sc + ay * so;
      acc.z = acc.z * sc + az * so;
      acc.w = acc.w * sc + aw * so;
      m = nm;
    }
    if (g == 0) {
      float inv = (end > beg) ? 1.f / den : 0.f;
      float4 o4;
      o4.x = lrelu(acc.x * inv, 0.01f);
      o4.y = lrelu(acc.y * inv, 0.01f);
      o4.z = lrelu(acc.z * inv, 0.01f);
      o4.w = lrelu(acc.w * inv, 0.01f);
      *(float4*)&out[(size_t)r * 64 + c4] = o4;
    }
  }
}

// ---------------- fused Cheb v2: 4 edges/wave, 16 lanes/edge ----------------
// mode 1: out = c*(v_r - acc) - v_r                (v == T0)
// mode 2: out = 2*(c*(v_r - acc) - v_r) - t0_r     (v == T1)
__global__ __launch_bounds__(256) void k_cheb_fused(const float* __restrict__ v,
                                                    const float* __restrict__ t0,
                                                    const float* __restrict__ dinv,
                                                    const int* __restrict__ offs,
                                                    const int* __restrict__ csr_src,
                                                    float* __restrict__ out,
                                                    const float* __restrict__ lamf,
                                                    int n, int mode) {
  int lane = threadIdx.x & 63;
  int g  = lane >> 4;
  int li = lane & 15;
  int c4 = li * 4;
  int wid = (blockIdx.x * blockDim.x + threadIdx.x) >> 6;
  int nw = (gridDim.x * blockDim.x) >> 6;
  float cc = 2.f / lamf[0];
  for (int r = wid; r < n; r += nw) {
    int beg = offs[r], end = offs[r + 1];
    float dr = dinv[r];
    float4 acc; acc.x = acc.y = acc.z = acc.w = 0.f;
    for (int e4 = beg; e4 < end; e4 += 4) {
      int myE = e4 + g;
      bool act = myE < end;
      int s = act ? csr_src[myE] : 0;
      float ns = act ? dinv[s] * dr : 0.f;
      float4 vv = *(const float4*)&v[(size_t)s * 64 + c4];
      acc.x += ns * vv.x;
      acc.y += ns * vv.y;
      acc.z += ns * vv.z;
      acc.w += ns * vv.w;
    }
    #pragma unroll
    for (int o = 16; o < 64; o <<= 1) {
      acc.x += __shfl_xor(acc.x, o);
      acc.y += __shfl_xor(acc.y, o);
      acc.z += __shfl_xor(acc.z, o);
      acc.w += __shfl_xor(acc.w, o);
    }
    if (g == 0) {
      float4 vr = *(const float4*)&v[(size_t)r * 64 + c4];
      float4 o4;
      o4.x = cc * (vr.x - acc.x) - vr.x;
      o4.y = cc * (vr.y - acc.y) - vr.y;
      o4.z = cc * (vr.z - acc.z) - vr.z;
      o4.w = cc * (vr.w - acc.w) - vr.w;
      if (mode == 2) {
        float4 t = *(const float4*)&t0[(size_t)r * 64 + c4];
        o4.x = 2.f * o4.x - t.x;
        o4.y = 2.f * o4.y - t.y;
        o4.z = 2.f * o4.z - t.z;
        o4.w = 2.f * o4.w - t.w;
      }
      *(float4*)&out[(size_t)r * 64 + c4] = o4;
    }
  }
}

// ---------------- misc fused (wave per row) ----------------
__global__ void k_mask_select(const float* __restrict__ i2u, const float* __restrict__ pred,
                              float* __restrict__ out, int n) {
  int lane = threadIdx.x & 63;
  int wid = (blockIdx.x * blockDim.x + threadIdx.x) >> 6;
  int nw = (gridDim.x * blockDim.x) >> 6;
  for (int r = wid; r < n; r += nw) {
    float v = i2u[(size_t)r * 64 + lane];
    float s = v;
    for (int o = 32; o; o >>= 1) s += __shfl_xor(s, o);
    out[(size_t)r * 64 + lane] = (s != 0.f) ? v : pred[(size_t)r * 64 + lane];
  }
}

// out = a * b * softmax_row(a)
__global__ void k_softmax_mul(const float* __restrict__ a, const float* __restrict__ b,
                              float* __restrict__ out, int n) {
  int lane = threadIdx.x & 63;
  int wid = (blockIdx.x * blockDim.x + threadIdx.x) >> 6;
  int nw = (gridDim.x * blockDim.x) >> 6;
  for (int r = wid; r < n; r += nw) {
    size_t idx = (size_t)r * 64 + lane;
    float av = a[idx];
    float mx = av;
    for (int o = 32; o; o >>= 1) mx = fmaxf(mx, __shfl_xor(mx, o));
    float e = expf(av - mx);
    float s = e;
    for (int o = 32; o; o >>= 1) s += __shfl_xor(s, o);
    out[idx] = av * b[idx] * (e / s);
  }
}

// ---------------- host ----------------
extern "C" void kernel_launch(void* const* d_in, const int* in_sizes, int n_in,
                              void* d_out, int out_size, void* d_ws, size_t ws_size,
                              hipStream_t stream) {
  const float* emb      = (const float*)d_in[0];
  const float* bn0_g    = (const float*)d_in[1];
  const float* bn0_b    = (const float*)d_in[2];
  const float* gat_Wl   = (const float*)d_in[3];
  const float* gat_bl   = (const float*)d_in[4];
  const float* gat_Wr   = (const float*)d_in[5];
  const float* gat_br   = (const float*)d_in[6];
  const float* gat_attn = (const float*)d_in[7];
  const float* cheb_W   = (const float*)d_in[8];
  const float* cheb_b   = (const float*)d_in[9];
  const float* mlp_W    = (const float*)d_in[10];
  const float* mlp_b    = (const float*)d_in[11];
  const float* mlp_g    = (const float*)d_in[12];
  const float* mlp_beta = (const float*)d_in[13];
  const float* lam      = (const float*)d_in[14];
  const int* u2i_src = (const int*)d_in[15];
  const int* u2i_dst = (const int*)d_in[16];
  const int* rc_src  = (const int*)d_in[17];
  const int* rc_dst  = (const int*)d_in[18];
  const int* i2u_src = (const int*)d_in[19];
  const int* i2u_dst = (const int*)d_in[20];
  const int* sn_src  = (const int*)d_in[22];
  const int* sn_dst  = (const int*)d_in[23];
  const int* snn_src = (const int*)d_in[24];
  const int* snn_dst = (const int*)d_in[25];
  int E_u2i = in_sizes[15], E_rc = in_sizes[17], E_i2u = in_sizes[19];
  int E_sn = in_sizes[22], E_snn = in_sizes[24];

  float* Wp = (float*)d_ws;
  size_t off = 0;
  auto alloc = [&](size_t nf) { float* p = Wp + off; off += nf; return p; };
  float* e_tot = alloc((size_t)TOTAL * 64);     // 30.7 MB
  float* POOL  = alloc((size_t)600000 * 64);    // 153.6 MB
  int*   csr_src = (int*)alloc(1500000);        // 6 MB
  int*   offs    = (int*)alloc(200064);
  int*   cnt_cur = (int*)alloc(200064);
  int*   bsums   = (int*)alloc(1024);
  float* dinv  = alloc(TOTAL);
  float* sums  = alloc(128);
  // total ~192.4 MB

  auto R = [&](size_t row) { return POOL + row * 64; };
  float* outP = (float*)d_out;                  // f32 output
  float* outS = outP + (size_t)PRED * 64;

  auto gemm = [&](const float* A, const float* Wm, const float* bias, float* C, int n, int acc, int relu) {
    k_gemm64<<<(n + 127) / 128, 128, 0, stream>>>(A, Wm, bias, C, n, acc, relu);
  };
  auto stats = [&](const float* x, int n) {
    hipMemsetAsync(sums, 0, 128 * 4, stream);
    k_bn_stats<<<512, 256, 0, stream>>>(x, n, sums);
  };
  auto build_csr = [&](const int* src, const int* dst, int E, int n) {
    int NB = (n + 256) / 256;   // covers n+1 elements
    hipMemsetAsync(cnt_cur, 0, (size_t)n * 4, stream);
    k_hist<<<2048, 256, 0, stream>>>(dst, cnt_cur, E);
    k_scan_part<<<NB, 256, 0, stream>>>(cnt_cur, bsums, n);
    k_scan_tops<<<1, 256, 0, stream>>>(bsums, NB);
    k_scan_apply<<<NB, 256, 0, stream>>>(cnt_cur, bsums, offs, n);
    k_permute<<<2048, 256, 0, stream>>>(src, dst, cnt_cur, csr_src, E);
  };
  auto gat = [&](int i, const float* fs, const float* fd, int n, float* out) {
    k_gat_fused<<<(n + 3) / 4, 256, 0, stream>>>(fs, fd, gat_attn + i * 64, offs, csr_src, out, n);
  };

  // ---- bn0 ----
  stats(emb, NODES);
  k_bn0_apply<<<2048, 256, 0, stream>>>(emb, e_tot, R(0), sums, bn0_g, bn0_b);

  // ---- gat0: u2i_emb -> R(0) (in-place over uie) ----
  build_csr(u2i_src, u2i_dst, E_u2i, NUI);
  gemm(R(0), gat_Wl + 0 * 4096, gat_bl + 0, R(200000), NUI, 0, 0);
  gemm(R(0), gat_Wr + 0 * 4096, gat_br + 0, R(400000), NUI, 0, 0);
  gat(0, R(200000), R(400000), NUI, R(0));

  // ---- gat1: iie -> R(0)[:PRED] ----
  build_csr(rc_src, rc_dst, E_rc, NUI);
  gemm(R(0), gat_Wl + 1 * 4096, gat_bl + 64, R(200000), NUI, 0, 0);
  gemm(R(0), gat_Wr + 1 * 4096, gat_br + 64, R(400000), NUI, 0, 0);
  gat(1, R(200000), R(400000), NUI, R(0));

  // ---- gat2: i2u_emb -> R(300000) ----
  build_csr(i2u_src, i2u_dst, E_i2u, PRED);
  gemm(e_tot, gat_Wl + 2 * 4096, gat_bl + 128, R(200000), PRED, 0, 0);
  gemm(e_tot, gat_Wr + 2 * 4096, gat_br + 128, R(400000), PRED, 0, 0);
  gat(2, R(200000), R(400000), PRED, R(300000));

  // ---- soc -> R(400000) ----
  k_mask_select<<<2048, 256, 0, stream>>>(R(300000), e_tot, R(400000), PRED);

  // ---- gat3: sie -> R(300000) ----
  build_csr(sn_src, sn_dst, E_sn, PRED);
  gemm(R(400000), gat_Wl + 3 * 4096, gat_bl + 192, R(200000), PRED, 0, 0);
  gemm(R(400000), gat_Wr + 3 * 4096, gat_br + 192, R(500000), PRED, 0, 0);
  gat(3, R(200000), R(500000), PRED, R(300000));

  // ---- mlp0: user_item -> R(0)[:PRED] (via scratch R(100000)) ----
  gemm(R(0), mlp_W + 0 * 8192, mlp_b + 0, R(100000), PRED, 0, 0);
  gemm(R(300000), mlp_W + 0 * 8192 + 4096, nullptr, R(100000), PRED, 1, 0);
  stats(R(100000), PRED);
  k_bn_apply<<<2048, 256, 0, stream>>>(R(100000), R(0), sums, mlp_g + 0, mlp_beta + 0, PRED, 1);

  // ---- snn CSR (used by cheb x4 and gat4) ----
  build_csr(snn_src, snn_dst, E_snn, TOTAL);
  k_dinv<<<256, 256, 0, stream>>>(offs, dinv, TOTAL);

  auto cheb = [&](const float* T0, float* T1, float* T2, float* outC) {
    k_cheb_fused<<<(TOTAL + 3) / 4, 256, 0, stream>>>(T0, T0, dinv, offs, csr_src, T1, lam, TOTAL, 1);
    k_cheb_fused<<<(TOTAL + 3) / 4, 256, 0, stream>>>(T1, T0, dinv, offs, csr_src, T2, lam, TOTAL, 2);
    gemm(T0, cheb_W + 0,    cheb_b, outC, TOTAL, 0, 0);
    gemm(T1, cheb_W + 4096, nullptr, outC, TOTAL, 1, 0);
    gemm(T2, cheb_W + 8192, nullptr, outC, TOTAL, 1, 1);
  };
  cheb(e_tot, R(100000), R(220000), R(340000));       // h1 -> R(340000)
  cheb(R(340000), R(100000), R(220000), R(460000));   // h2 -> R(460000)

  // ---- gat4: user_social -> R(460000) ----
  gemm(R(460000), gat_Wl + 4 * 4096, gat_bl + 256, R(100000), TOTAL, 0, 0);
  gemm(R(460000), gat_Wr + 4 * 4096, gat_br + 256, R(220000), TOTAL, 0, 0);
  gat(4, R(100000), R(220000), TOTAL, R(460000));

  // ---- mlp1: h_uP -> R(100000) ----
  gemm(R(0), mlp_W + 1 * 8192, mlp_b + 64, R(100000), PRED, 0, 0);
  gemm(e_tot, mlp_W + 1 * 8192 + 4096, nullptr, R(100000), PRED, 1, 0);
  stats(R(100000), PRED);
  k_bn_apply<<<2048, 256, 0, stream>>>(R(100000), R(100000), sums, mlp_g + 64, mlp_beta + 64, PRED, 1);

  // ---- mlp2: h_uS -> R(200000) ----
  gemm(R(460000), mlp_W + 2 * 8192, mlp_b + 128, R(200000), PRED, 0, 0);
  gemm(e_tot, mlp_W + 2 * 8192 + 4096, nullptr, R(200000), PRED, 1, 0);
  stats(R(200000), PRED);
  k_bn_apply<<<2048, 256, 0, stream>>>(R(200000), R(200000), sums, mlp_g + 128, mlp_beta + 128, PRED, 1);

  // ---- final P ----
  k_softmax_mul<<<2048, 256, 0, stream>>>(R(100000), R(200000), R(300000), PRED);
  gemm(R(300000), mlp_W + 3 * 8192, mlp_b + 192, R(400000), PRED, 0, 0);
  gemm(R(100000), mlp_W + 3 * 8192 + 4096, nullptr, R(400000), PRED, 1, 0);
  stats(R(400000), PRED);
  k_bn_apply<<<2048, 256, 0, stream>>>(R(400000), outP, sums, mlp_g + 192, mlp_beta + 192, PRED, 1);

  // ---- final S ----
  k_softmax_mul<<<2048, 256, 0, stream>>>(R(200000), R(100000), R(300000), PRED);
  gemm(R(300000), mlp_W + 4 * 8192, mlp_b + 256, R(400000), PRED, 0, 0);
  gemm(R(200000), mlp_W + 4 * 8192 + 4096, nullptr, R(400000), PRED, 1, 0);
  stats(R(400000), PRED);
  k_bn_apply<<<2048, 256, 0, stream>>>(R(400000), outS, sums, mlp_g + 256, mlp_beta + 256, PRED, 1);
}

// Round 5
// 2331.252 us; speedup vs baseline: 2.3809x; 1.2154x over previous
//
#include <hip/hip_runtime.h>
#include <math.h>

static const int PRED  = 100000;
static const int TOTAL = 120000;
static const int ITEM  = 100000;
static const int NUI   = PRED + ITEM;    // 200000
static const int NODES = TOTAL + ITEM;   // 220000
#define BN_EPS 1e-5f
#define MNEG -1e30f
#define WNEG -2e30f

__device__ inline float lrelu(float v, float s) { return v > 0.f ? v : s * v; }

// ---------------- batchnorm ----------------
__global__ void k_bn_stats(const float* __restrict__ x, int n, float* __restrict__ sums) {
  __shared__ float ls[256], ls2[256];
  int t = threadIdx.x;
  int col = t & 63;
  float s = 0.f, s2 = 0.f;
  for (int r = blockIdx.x * 4 + (t >> 6); r < n; r += gridDim.x * 4) {
    float v = x[(size_t)r * 64 + col];
    s += v; s2 += v * v;
  }
  ls[t] = s; ls2[t] = s2;
  __syncthreads();
  if (t < 64) {
    atomicAdd(&sums[t],      ls[t] + ls[t + 64] + ls[t + 128] + ls[t + 192]);
    atomicAdd(&sums[64 + t], ls2[t] + ls2[t + 64] + ls2[t + 128] + ls2[t + 192]);
  }
}

__global__ void k_bn_apply(const float* __restrict__ x, float* __restrict__ y,
                           const float* __restrict__ sums,
                           const float* __restrict__ g, const float* __restrict__ b,
                           int n, int relu) {
  size_t tot = (size_t)n * 64;
  size_t i = (size_t)blockIdx.x * blockDim.x + threadIdx.x;
  size_t st = (size_t)gridDim.x * blockDim.x;
  float inv_n = 1.f / (float)n;
  for (; i < tot; i += st) {
    int c = (int)(i & 63);
    float mean = sums[c] * inv_n;
    float var = fmaxf(sums[64 + c] * inv_n - mean * mean, 0.f);
    float o = (x[i] - mean) * rsqrtf(var + BN_EPS) * g[c] + b[c];
    if (relu) o = lrelu(o, 0.01f);
    y[i] = o;
  }
}

__global__ void k_bn0_apply(const float* __restrict__ x, float* __restrict__ e_tot,
                            float* __restrict__ uie, const float* __restrict__ sums,
                            const float* __restrict__ g, const float* __restrict__ b) {
  size_t tot = (size_t)NODES * 64;
  size_t i = (size_t)blockIdx.x * blockDim.x + threadIdx.x;
  size_t st = (size_t)gridDim.x * blockDim.x;
  float inv_n = 1.f / (float)NODES;
  for (; i < tot; i += st) {
    int c = (int)(i & 63);
    size_t row = i >> 6;
    float mean = sums[c] * inv_n;
    float var = fmaxf(sums[64 + c] * inv_n - mean * mean, 0.f);
    float o = (x[i] - mean) * rsqrtf(var + BN_EPS) * g[c] + b[c];
    if (row < (size_t)TOTAL) e_tot[i] = o;
    else uie[((row - TOTAL) + PRED) * 64 + c] = o;
    if (row < (size_t)PRED) uie[i] = o;
  }
}

// ---------------- fused GEMMs (128 rows/block, 128 threads, 8x8/thread) ----------------
// dual-output: FS = A@Wl+bl ; FD = A@Wr+br  (stage A once)
__global__ __launch_bounds__(128) void k_gemm_dual(const float* __restrict__ A,
    const float* __restrict__ Wl, const float* __restrict__ bl,
    const float* __restrict__ Wr, const float* __restrict__ br,
    float* __restrict__ FS, float* __restrict__ FD, int n) {
  __shared__ float As[128][65];
  __shared__ float Ws[64][68];
  int t = threadIdx.x;
  int row0 = blockIdx.x * 128;
  for (int i = t; i < 2048; i += 128) {
    int r = i >> 4, c = (i & 15) * 4, gr = row0 + r;
    float4 a;
    if (gr < n) a = *(const float4*)&A[(size_t)gr * 64 + c];
    else { a.x = a.y = a.z = a.w = 0.f; }
    As[r][c] = a.x; As[r][c + 1] = a.y; As[r][c + 2] = a.z; As[r][c + 3] = a.w;
  }
  int cg = (t & 7) * 8;
  int rg = (t >> 3) * 8;
  for (int s = 0; s < 2; ++s) {
    const float* Wm = s ? Wr : Wl;
    const float* bias = s ? br : bl;
    __syncthreads();
    for (int i = t; i < 4096; i += 128) Ws[i >> 6][i & 63] = Wm[i];
    __syncthreads();
    float bb[8];
    *(float4*)&bb[0] = *(const float4*)&bias[cg];
    *(float4*)&bb[4] = *(const float4*)&bias[cg + 4];
    float acc[8][8];
    #pragma unroll
    for (int i = 0; i < 8; ++i)
      #pragma unroll
      for (int j = 0; j < 8; ++j) acc[i][j] = bb[j];
    for (int k = 0; k < 64; ++k) {
      float w[8], a[8];
      *(float4*)&w[0] = *(const float4*)&Ws[k][cg];
      *(float4*)&w[4] = *(const float4*)&Ws[k][cg + 4];
      #pragma unroll
      for (int i = 0; i < 8; ++i) a[i] = As[rg + i][k];
      #pragma unroll
      for (int i = 0; i < 8; ++i)
        #pragma unroll
        for (int j = 0; j < 8; ++j)
          acc[i][j] += a[i] * w[j];
    }
    float* C = s ? FD : FS;
    #pragma unroll
    for (int i = 0; i < 8; ++i) {
      int gr = row0 + rg + i;
      if (gr < n) {
        float4 o0, o1;
        o0.x = acc[i][0]; o0.y = acc[i][1]; o0.z = acc[i][2]; o0.w = acc[i][3];
        o1.x = acc[i][4]; o1.y = acc[i][5]; o1.z = acc[i][6]; o1.w = acc[i][7];
        *(float4*)&C[(size_t)gr * 64 + cg] = o0;
        *(float4*)&C[(size_t)gr * 64 + cg + 4] = o1;
      }
    }
  }
}

// concat GEMM: C = A1@W[0:64] + A2@W[64:128] (+ A3@W[128:192]) + bias, optional lrelu
__global__ __launch_bounds__(128) void k_gemm_cat(const float* __restrict__ A1,
    const float* __restrict__ A2, const float* __restrict__ A3,
    const float* __restrict__ Wm, const float* __restrict__ bias,
    float* __restrict__ C, int n, int nseg, int relu) {
  __shared__ float As[128][65];
  __shared__ float Ws[64][68];
  int t = threadIdx.x;
  int row0 = blockIdx.x * 128;
  int cg = (t & 7) * 8;
  int rg = (t >> 3) * 8;
  float bb[8];
  *(float4*)&bb[0] = *(const float4*)&bias[cg];
  *(float4*)&bb[4] = *(const float4*)&bias[cg + 4];
  float acc[8][8];
  #pragma unroll
  for (int i = 0; i < 8; ++i)
    #pragma unroll
    for (int j = 0; j < 8; ++j) acc[i][j] = bb[j];
  for (int s = 0; s < nseg; ++s) {
    const float* A = (s == 0) ? A1 : (s == 1) ? A2 : A3;
    __syncthreads();
    for (int i = t; i < 4096; i += 128) Ws[i >> 6][i & 63] = Wm[s * 4096 + i];
    for (int i = t; i < 2048; i += 128) {
      int r = i >> 4, c = (i & 15) * 4, gr = row0 + r;
      float4 a;
      if (gr < n) a = *(const float4*)&A[(size_t)gr * 64 + c];
      else { a.x = a.y = a.z = a.w = 0.f; }
      As[r][c] = a.x; As[r][c + 1] = a.y; As[r][c + 2] = a.z; As[r][c + 3] = a.w;
    }
    __syncthreads();
    for (int k = 0; k < 64; ++k) {
      float w[8], a[8];
      *(float4*)&w[0] = *(const float4*)&Ws[k][cg];
      *(float4*)&w[4] = *(const float4*)&Ws[k][cg + 4];
      #pragma unroll
      for (int i = 0; i < 8; ++i) a[i] = As[rg + i][k];
      #pragma unroll
      for (int i = 0; i < 8; ++i)
        #pragma unroll
        for (int j = 0; j < 8; ++j)
          acc[i][j] += a[i] * w[j];
    }
  }
  #pragma unroll
  for (int i = 0; i < 8; ++i) {
    int gr = row0 + rg + i;
    if (gr < n) {
      float4 o0, o1;
      o0.x = acc[i][0]; o0.y = acc[i][1]; o0.z = acc[i][2]; o0.w = acc[i][3];
      o1.x = acc[i][4]; o1.y = acc[i][5]; o1.z = acc[i][6]; o1.w = acc[i][7];
      if (relu) {
        o0.x = lrelu(o0.x, 0.01f); o0.y = lrelu(o0.y, 0.01f); o0.z = lrelu(o0.z, 0.01f); o0.w = lrelu(o0.w, 0.01f);
        o1.x = lrelu(o1.x, 0.01f); o1.y = lrelu(o1.y, 0.01f); o1.z = lrelu(o1.z, 0.01f); o1.w = lrelu(o1.w, 0.01f);
      }
      *(float4*)&C[(size_t)gr * 64 + cg] = o0;
      *(float4*)&C[(size_t)gr * 64 + cg + 4] = o1;
    }
  }
}

// ---------------- CSR build v2: deterministic bucket sort, no global atomics ----------------
// bucket = dst >> 7 (max 1563 buckets for n=200000)
__global__ __launch_bounds__(512) void k_bhist(const int* __restrict__ dst, int* __restrict__ M,
                                               int E, int nbuck, int chunk) {
  __shared__ int h[1600];
  int t = threadIdx.x, b = blockIdx.x;
  for (int k = t; k < nbuck; k += 512) h[k] = 0;
  __syncthreads();
  int beg = b * chunk, end = min(E, beg + chunk);
  for (int i = beg + t; i < end; i += 512) atomicAdd(&h[dst[i] >> 7], 1);
  __syncthreads();
  for (int k = t; k < nbuck; k += 512) M[k * 64 + b] = h[k];
}

__global__ void k_scan_part(const int* __restrict__ counts, int* __restrict__ bsums, int n) {
  __shared__ int sh[256];
  int t = threadIdx.x;
  int i = blockIdx.x * 256 + t;
  sh[t] = (i < n) ? counts[i] : 0;
  __syncthreads();
  for (int o = 128; o; o >>= 1) {
    if (t < o) sh[t] += sh[t + o];
    __syncthreads();
  }
  if (t == 0) bsums[blockIdx.x] = sh[0];
}

__global__ void k_scan_tops(int* __restrict__ bsums, int nb) {
  __shared__ int sh[256];
  int t = threadIdx.x;
  int carry = 0;
  for (int base = 0; base < nb; base += 256) {
    int i = base + t;
    int v = (i < nb) ? bsums[i] : 0;
    __syncthreads();
    sh[t] = v;
    __syncthreads();
    for (int o = 1; o < 256; o <<= 1) {
      int tv = (t >= o) ? sh[t - o] : 0;
      __syncthreads();
      sh[t] += tv;
      __syncthreads();
    }
    int incl = sh[t];
    int total = sh[255];
    if (i < nb) bsums[i] = incl - v + carry;
    carry += total;
  }
}

__global__ void k_scan_apply_ip(int* __restrict__ cnts, const int* __restrict__ bsums, int n) {
  __shared__ int sh[256];
  int t = threadIdx.x;
  int i = blockIdx.x * 256 + t;
  int v = (i < n) ? cnts[i] : 0;
  sh[t] = v;
  __syncthreads();
  for (int o = 1; o < 256; o <<= 1) {
    int tv = (t >= o) ? sh[t - o] : 0;
    __syncthreads();
    sh[t] += tv;
    __syncthreads();
  }
  if (i < n) cnts[i] = sh[t] - v + bsums[blockIdx.x];
}

__global__ __launch_bounds__(512) void k_bscatter(const int* __restrict__ src, const int* __restrict__ dst,
                                                  const int* __restrict__ M, unsigned int* __restrict__ tmp,
                                                  int E, int nbuck, int chunk) {
  __shared__ int cur[1600];
  int t = threadIdx.x, b = blockIdx.x;
  for (int k = t; k < nbuck; k += 512) cur[k] = M[k * 64 + b];
  __syncthreads();
  int beg = b * chunk, end = min(E, beg + chunk);
  for (int i = beg + t; i < end; i += 512) {
    int d = dst[i];
    int pos = atomicAdd(&cur[d >> 7], 1);
    tmp[pos] = ((unsigned int)(d & 127) << 25) | (unsigned int)src[i];
  }
}

__global__ __launch_bounds__(256) void k_bfinal(const unsigned int* __restrict__ tmp,
                                                const int* __restrict__ M,
                                                int* __restrict__ offs, int* __restrict__ csr,
                                                int E, int nbuck, int n) {
  __shared__ int h[128];
  int t = threadIdx.x, k = blockIdx.x;
  int base = M[k * 64];
  int next = (k + 1 < nbuck) ? M[(k + 1) * 64] : E;
  if (t < 128) h[t] = 0;
  __syncthreads();
  for (int i = base + t; i < next; i += 256) atomicAdd(&h[tmp[i] >> 25], 1);
  __syncthreads();
  if (t == 0) { int s = 0; for (int j = 0; j < 128; ++j) { int c = h[j]; h[j] = s; s += c; } }
  __syncthreads();
  int r0 = k << 7;
  if (t < 128 && r0 + t < n) offs[r0 + t] = base + h[t];
  if (k == nbuck - 1 && t == 0) offs[n] = E;
  __syncthreads();
  for (int i = base + t; i < next; i += 256) {
    unsigned int v = tmp[i];
    int rl = (int)(v >> 25);
    int pos = base + atomicAdd(&h[rl], 1);
    csr[pos] = (int)(v & 0x01FFFFFFu);
  }
}

__global__ void k_dinv(const int* __restrict__ offs, float* __restrict__ dinv, int n) {
  int i = blockIdx.x * blockDim.x + threadIdx.x;
  int st = gridDim.x * blockDim.x;
  for (; i < n; i += st) dinv[i] = rsqrtf(fmaxf((float)(offs[i + 1] - offs[i]), 1.f));
}

// ---------------- fused GAT: 4 edges/wave, 16 lanes/edge, float4/lane ----------------
__global__ __launch_bounds__(256) void k_gat_fused(const float* __restrict__ fs,
                                                   const float* __restrict__ fd,
                                                   const float* __restrict__ attn,
                                                   const int* __restrict__ offs,
                                                   const int* __restrict__ csr_src,
                                                   float* __restrict__ out, int n) {
  int lane = threadIdx.x & 63;
  int g  = lane >> 4;          // edge group 0..3
  int li = lane & 15;          // channel quad 0..15
  int c4 = li * 4;
  int wid = (blockIdx.x * blockDim.x + threadIdx.x) >> 6;
  int nw = (gridDim.x * blockDim.x) >> 6;
  float4 ak = *(const float4*)&attn[c4];
  for (int r = wid; r < n; r += nw) {
    int beg = offs[r], end = offs[r + 1];
    float4 fdv = *(const float4*)&fd[(size_t)r * 64 + c4];
    float m = MNEG, den = 0.f;
    float4 acc; acc.x = acc.y = acc.z = acc.w = 0.f;
    for (int e4 = beg; e4 < end; e4 += 4) {
      int myE = e4 + g;
      bool act = myE < end;
      int s = act ? csr_src[myE] : 0;
      float4 fsv = *(const float4*)&fs[(size_t)s * 64 + c4];
      float w = ak.x * lrelu(fsv.x + fdv.x, 0.2f)
              + ak.y * lrelu(fsv.y + fdv.y, 0.2f)
              + ak.z * lrelu(fsv.z + fdv.z, 0.2f)
              + ak.w * lrelu(fsv.w + fdv.w, 0.2f);
      w += __shfl_xor(w, 1);
      w += __shfl_xor(w, 2);
      w += __shfl_xor(w, 4);
      w += __shfl_xor(w, 8);
      if (!act) w = WNEG;
      float nm = fmaxf(m, w);
      float sc = __expf(m - nm);
      float p  = __expf(w - nm);
      den = den * sc + p;
      acc.x = acc.x * sc + p * fsv.x;
      acc.y = acc.y * sc + p * fsv.y;
      acc.z = acc.z * sc + p * fsv.z;
      acc.w = acc.w * sc + p * fsv.w;
      m = nm;
    }
    #pragma unroll
    for (int o = 16; o < 64; o <<= 1) {
      float mo   = __shfl_xor(m, o);
      float deno = __shfl_xor(den, o);
      float ax = __shfl_xor(acc.x, o);
      float ay = __shfl_xor(acc.y, o);
      float az = __shfl_xor(acc.z, o);
      float aw = __shfl_xor(acc.w, o);
      float nm = fmaxf(m, mo);
      float sc = __expf(m - nm);
      float so = __expf(mo - nm);
      den = den * sc + deno * so;
      acc.x = acc.x * sc + ax * so;
      acc.y = acc.y * sc + ay * so;
      acc.z = acc.z * sc + az * so;
      acc.w = acc.w * sc + aw * so;
      m = nm;
    }
    if (g == 0) {
      float inv = (end > beg) ? 1.f / den : 0.f;
      float4 o4;
      o4.x = lrelu(acc.x * inv, 0.01f);
      o4.y = lrelu(acc.y * inv, 0.01f);
      o4.z = lrelu(acc.z * inv, 0.01f);
      o4.w = lrelu(acc.w * inv, 0.01f);
      *(float4*)&out[(size_t)r * 64 + c4] = o4;
    }
  }
}

// ---------------- fused Cheb: 4 edges/wave, 16 lanes/edge ----------------
__global__ __launch_bounds__(256) void k_cheb_fused(const float* __restrict__ v,
                                                    const float* __restrict__ t0,
                                                    const float* __restrict__ dinv,
                                                    const int* __restrict__ offs,
                                                    const int* __restrict__ csr_src,
                                                    float* __restrict__ out,
                                                    const float* __restrict__ lamf,
                                                    int n, int mode) {
  int lane = threadIdx.x & 63;
  int g  = lane >> 4;
  int li = lane & 15;
  int c4 = li * 4;
  int wid = (blockIdx.x * blockDim.x + threadIdx.x) >> 6;
  int nw = (gridDim.x * blockDim.x) >> 6;
  float cc = 2.f / lamf[0];
  for (int r = wid; r < n; r += nw) {
    int beg = offs[r], end = offs[r + 1];
    float dr = dinv[r];
    float4 acc; acc.x = acc.y = acc.z = acc.w = 0.f;
    for (int e4 = beg; e4 < end; e4 += 4) {
      int myE = e4 + g;
      bool act = myE < end;
      int s = act ? csr_src[myE] : 0;
      float ns = act ? dinv[s] * dr : 0.f;
      float4 vv = *(const float4*)&v[(size_t)s * 64 + c4];
      acc.x += ns * vv.x;
      acc.y += ns * vv.y;
      acc.z += ns * vv.z;
      acc.w += ns * vv.w;
    }
    #pragma unroll
    for (int o = 16; o < 64; o <<= 1) {
      acc.x += __shfl_xor(acc.x, o);
      acc.y += __shfl_xor(acc.y, o);
      acc.z += __shfl_xor(acc.z, o);
      acc.w += __shfl_xor(acc.w, o);
    }
    if (g == 0) {
      float4 vr = *(const float4*)&v[(size_t)r * 64 + c4];
      float4 o4;
      o4.x = cc * (vr.x - acc.x) - vr.x;
      o4.y = cc * (vr.y - acc.y) - vr.y;
      o4.z = cc * (vr.z - acc.z) - vr.z;
      o4.w = cc * (vr.w - acc.w) - vr.w;
      if (mode == 2) {
        float4 t = *(const float4*)&t0[(size_t)r * 64 + c4];
        o4.x = 2.f * o4.x - t.x;
        o4.y = 2.f * o4.y - t.y;
        o4.z = 2.f * o4.z - t.z;
        o4.w = 2.f * o4.w - t.w;
      }
      *(float4*)&out[(size_t)r * 64 + c4] = o4;
    }
  }
}

// ---------------- misc fused (wave per row) ----------------
__global__ void k_mask_select(const float* __restrict__ i2u, const float* __restrict__ pred,
                              float* __restrict__ out, int n) {
  int lane = threadIdx.x & 63;
  int wid = (blockIdx.x * blockDim.x + threadIdx.x) >> 6;
  int nw = (gridDim.x * blockDim.x) >> 6;
  for (int r = wid; r < n; r += nw) {
    float v = i2u[(size_t)r * 64 + lane];
    float s = v;
    for (int o = 32; o; o >>= 1) s += __shfl_xor(s, o);
    out[(size_t)r * 64 + lane] = (s != 0.f) ? v : pred[(size_t)r * 64 + lane];
  }
}

__global__ void k_softmax_mul(const float* __restrict__ a, const float* __restrict__ b,
                              float* __restrict__ out, int n) {
  int lane = threadIdx.x & 63;
  int wid = (blockIdx.x * blockDim.x + threadIdx.x) >> 6;
  int nw = (gridDim.x * blockDim.x) >> 6;
  for (int r = wid; r < n; r += nw) {
    size_t idx = (size_t)r * 64 + lane;
    float av = a[idx];
    float mx = av;
    for (int o = 32; o; o >>= 1) mx = fmaxf(mx, __shfl_xor(mx, o));
    float e = expf(av - mx);
    float s = e;
    for (int o = 32; o; o >>= 1) s += __shfl_xor(s, o);
    out[idx] = av * b[idx] * (e / s);
  }
}

// ---------------- host ----------------
extern "C" void kernel_launch(void* const* d_in, const int* in_sizes, int n_in,
                              void* d_out, int out_size, void* d_ws, size_t ws_size,
                              hipStream_t stream) {
  const float* emb      = (const float*)d_in[0];
  const float* bn0_g    = (const float*)d_in[1];
  const float* bn0_b    = (const float*)d_in[2];
  const float* gat_Wl   = (const float*)d_in[3];
  const float* gat_bl   = (const float*)d_in[4];
  const float* gat_Wr   = (const float*)d_in[5];
  const float* gat_br   = (const float*)d_in[6];
  const float* gat_attn = (const float*)d_in[7];
  const float* cheb_W   = (const float*)d_in[8];
  const float* cheb_b   = (const float*)d_in[9];
  const float* mlp_W    = (const float*)d_in[10];
  const float* mlp_b    = (const float*)d_in[11];
  const float* mlp_g    = (const float*)d_in[12];
  const float* mlp_beta = (const float*)d_in[13];
  const float* lam      = (const float*)d_in[14];
  const int* u2i_src = (const int*)d_in[15];
  const int* u2i_dst = (const int*)d_in[16];
  const int* rc_src  = (const int*)d_in[17];
  const int* rc_dst  = (const int*)d_in[18];
  const int* i2u_src = (const int*)d_in[19];
  const int* i2u_dst = (const int*)d_in[20];
  const int* sn_src  = (const int*)d_in[22];
  const int* sn_dst  = (const int*)d_in[23];
  const int* snn_src = (const int*)d_in[24];
  const int* snn_dst = (const int*)d_in[25];
  int E_u2i = in_sizes[15], E_rc = in_sizes[17], E_i2u = in_sizes[19];
  int E_sn = in_sizes[22], E_snn = in_sizes[24];

  float* Wp = (float*)d_ws;
  size_t off = 0;
  auto alloc = [&](size_t nf) { float* p = Wp + off; off += nf; return p; };
  float* e_tot = alloc((size_t)TOTAL * 64);     // 30.7 MB
  float* POOL  = alloc((size_t)600000 * 64);    // 153.6 MB
  int*   csr_src = (int*)alloc(1500000);        // 6 MB
  int*   offs    = (int*)alloc(200064);
  float* spare   = alloc(200064);               // (unused, keeps layout)
  int*   bsums   = (int*)alloc(1024);
  float* dinv  = alloc(TOTAL);
  float* sums  = alloc(128);
  // total ~192.4 MB (unchanged)

  auto R = [&](size_t row) { return POOL + row * 64; };
  // transient CSR-build scratch carved from POOL rows that are dead during every build:
  unsigned int* tmp_e = (unsigned int*)R(520000);   // need 1.5M u32 = ~23438 rows
  int*          Mbuf  = (int*)R(545000);            // up to 1563*64 = 100,032 ints
  (void)spare;

  float* outP = (float*)d_out;                  // f32 output
  float* outS = outP + (size_t)PRED * 64;

  auto stats = [&](const float* x, int n) {
    hipMemsetAsync(sums, 0, 128 * 4, stream);
    k_bn_stats<<<512, 256, 0, stream>>>(x, n, sums);
  };
  auto build_csr = [&](const int* src, const int* dst, int E, int n) {
    int nbuck = (n + 127) >> 7;
    int chunk = (E + 63) / 64;
    int L = nbuck * 64;
    int NB = (L + 255) / 256;
    k_bhist<<<64, 512, 0, stream>>>(dst, Mbuf, E, nbuck, chunk);
    k_scan_part<<<NB, 256, 0, stream>>>(Mbuf, bsums, L);
    k_scan_tops<<<1, 256, 0, stream>>>(bsums, NB);
    k_scan_apply_ip<<<NB, 256, 0, stream>>>(Mbuf, bsums, L);
    k_bscatter<<<64, 512, 0, stream>>>(src, dst, Mbuf, tmp_e, E, nbuck, chunk);
    k_bfinal<<<nbuck, 256, 0, stream>>>(tmp_e, Mbuf, offs, csr_src, E, nbuck, n);
  };
  auto gat = [&](int i, const float* fs, const float* fd, int n, float* out) {
    k_gat_fused<<<(n + 3) / 4, 256, 0, stream>>>(fs, fd, gat_attn + i * 64, offs, csr_src, out, n);
  };
  auto gat_gemms = [&](int i, const float* A, float* fs, float* fd, int n) {
    k_gemm_dual<<<(n + 127) / 128, 128, 0, stream>>>(A, gat_Wl + i * 4096, gat_bl + i * 64,
                                                     gat_Wr + i * 4096, gat_br + i * 64, fs, fd, n);
  };
  auto cat2 = [&](const float* A1, const float* A2, const float* Wm, const float* bias,
                  float* C, int n) {
    k_gemm_cat<<<(n + 127) / 128, 128, 0, stream>>>(A1, A2, nullptr, Wm, bias, C, n, 2, 0);
  };

  // ---- bn0 ----
  stats(emb, NODES);
  k_bn0_apply<<<2048, 256, 0, stream>>>(emb, e_tot, R(0), sums, bn0_g, bn0_b);

  // ---- gat0: u2i_emb -> R(0) (in-place over uie) ----
  build_csr(u2i_src, u2i_dst, E_u2i, NUI);
  gat_gemms(0, R(0), R(200000), R(400000), NUI);
  gat(0, R(200000), R(400000), NUI, R(0));

  // ---- gat1: iie -> R(0)[:PRED] ----
  build_csr(rc_src, rc_dst, E_rc, NUI);
  gat_gemms(1, R(0), R(200000), R(400000), NUI);
  gat(1, R(200000), R(400000), NUI, R(0));

  // ---- gat2: i2u_emb -> R(300000) ----
  build_csr(i2u_src, i2u_dst, E_i2u, PRED);
  gat_gemms(2, e_tot, R(200000), R(400000), PRED);
  gat(2, R(200000), R(400000), PRED, R(300000));

  // ---- soc -> R(400000) ----
  k_mask_select<<<2048, 256, 0, stream>>>(R(300000), e_tot, R(400000), PRED);

  // ---- gat3: sie -> R(300000) ----
  build_csr(sn_src, sn_dst, E_sn, PRED);
  gat_gemms(3, R(400000), R(200000), R(500000), PRED);
  gat(3, R(200000), R(500000), PRED, R(300000));

  // ---- mlp0: user_item -> R(0)[:PRED] (via scratch R(100000)) ----
  cat2(R(0), R(300000), mlp_W + 0 * 8192, mlp_b + 0, R(100000), PRED);
  stats(R(100000), PRED);
  k_bn_apply<<<2048, 256, 0, stream>>>(R(100000), R(0), sums, mlp_g + 0, mlp_beta + 0, PRED, 1);

  // ---- snn CSR (used by cheb x4 and gat4) ----
  build_csr(snn_src, snn_dst, E_snn, TOTAL);
  k_dinv<<<256, 256, 0, stream>>>(offs, dinv, TOTAL);

  auto cheb = [&](const float* T0, float* T1, float* T2, float* outC) {
    k_cheb_fused<<<(TOTAL + 3) / 4, 256, 0, stream>>>(T0, T0, dinv, offs, csr_src, T1, lam, TOTAL, 1);
    k_cheb_fused<<<(TOTAL + 3) / 4, 256, 0, stream>>>(T1, T0, dinv, offs, csr_src, T2, lam, TOTAL, 2);
    k_gemm_cat<<<(TOTAL + 127) / 128, 128, 0, stream>>>(T0, T1, T2, cheb_W, cheb_b, outC, TOTAL, 3, 1);
  };
  cheb(e_tot, R(100000), R(220000), R(340000));       // h1 -> R(340000)
  cheb(R(340000), R(100000), R(220000), R(460000));   // h2 -> R(460000)

  // ---- gat4: user_social -> R(460000) ----
  gat_gemms(4, R(460000), R(100000), R(220000), TOTAL);
  gat(4, R(100000), R(220000), TOTAL, R(460000));

  // ---- mlp1: h_uP -> R(100000) ----
  cat2(R(0), e_tot, mlp_W + 1 * 8192, mlp_b + 64, R(100000), PRED);
  stats(R(100000), PRED);
  k_bn_apply<<<2048, 256, 0, stream>>>(R(100000), R(100000), sums, mlp_g + 64, mlp_beta + 64, PRED, 1);

  // ---- mlp2: h_uS -> R(200000) ----
  cat2(R(460000), e_tot, mlp_W + 2 * 8192, mlp_b + 128, R(200000), PRED);
  stats(R(200000), PRED);
  k_bn_apply<<<2048, 256, 0, stream>>>(R(200000), R(200000), sums, mlp_g + 128, mlp_beta + 128, PRED, 1);

  // ---- final P ----
  k_softmax_mul<<<2048, 256, 0, stream>>>(R(100000), R(200000), R(300000), PRED);
  cat2(R(300000), R(100000), mlp_W + 3 * 8192, mlp_b + 192, R(400000), PRED);
  stats(R(400000), PRED);
  k_bn_apply<<<2048, 256, 0, stream>>>(R(400000), outP, sums, mlp_g + 192, mlp_beta + 192, PRED, 1);

  // ---- final S ----
  k_softmax_mul<<<2048, 256, 0, stream>>>(R(200000), R(100000), R(300000), PRED);
  cat2(R(300000), R(200000), mlp_W + 4 * 8192, mlp_b + 256, R(400000), PRED);
  stats(R(400000), PRED);
  k_bn_apply<<<2048, 256, 0, stream>>>(R(400000), outS, sums, mlp_g + 256, mlp_beta + 256, PRED, 1);
}